// Round 5
// baseline (193.802 us; speedup 1.0000x reference)
//
#include <hip/hip_runtime.h>

#define BINS 10
#define BLOCK 256
#define GRID 2048

#define LOG2E 1.44269504088896340736f
#define LN2   0.69314718055994530942f

// ---------------------------------------------------------------------------
// For logit x with one-hot target bit tg, let y = tg ? -x : x. Then
//   g   = |sigmoid(x) - tg| = sigmoid(y) = u/(1+u),      u = e^y
//   bce = max(x,0) - x*tg + log1p(exp(-|x|)) = softplus(y) = ln(1+u)
// One exp2 + one rcp + one log2 per logit.
//
// Histogram cells are PRIVATE per thread (own column), accumulated with
// non-returning ds_add_f32 (atomicAdd on __shared__, result unused):
// in-order per thread -> deterministic, and no read-wait-add-write chain.
// ---------------------------------------------------------------------------

__global__ void ghmc_init(double* ws) {
    int i = threadIdx.x;
    if (i < 2 * BINS) ws[i] = 0.0;
}

__device__ __forceinline__ void proc(float y, float* __restrict__ cbase,
                                     float* __restrict__ sbase) {
    y = fminf(fmaxf(y, -80.0f), 80.0f);              // v_med3_f32 guard
    float u  = __builtin_amdgcn_exp2f(y * LOG2E);    // e^y
    float d  = 1.0f + u;
    float r  = __builtin_amdgcn_rcpf(d);
    float lg = __builtin_amdgcn_logf(d);             // log2(1+u)
    float sg = u * r;                                // sigmoid(y) = g in [0,1]
    float sp = lg * LN2;                             // softplus(y) = bce
    int b = (int)(sg * 10.0f);
    b = b > (BINS - 1) ? (BINS - 1) : b;
    atomicAdd(cbase + (b << 8), 1.0f);               // ds_add_f32 (no return)
    atomicAdd(sbase + (b << 8), sp);                 // ds_add_f32 (no return)
}

__device__ __forceinline__ void proc_row(float x0, float x1, int t,
                                         float* __restrict__ cbase,
                                         float* __restrict__ sbase) {
    // class0 flips iff t==0, class1 flips iff t==1 (t in {0,1})
    unsigned s0 = (unsigned)(t ^ 1) << 31;
    unsigned s1 = s0 ^ 0x80000000u;
    proc(__uint_as_float(__float_as_uint(x0) ^ s0), cbase, sbase);
    proc(__uint_as_float(__float_as_uint(x1) ^ s1), cbase, sbase);
}

template <int WRITE_MODE>  // 0 = per-block partials (deterministic), 1 = double atomics
__global__ __launch_bounds__(BLOCK, 8) void ghmc_main(
    const float4* __restrict__ pred4,   // one float4 = 2 rows' logits
    const int4*   __restrict__ tgt4,    // one int4   = 4 rows' targets (int32)
    float2* __restrict__ partials,      // [GRID][BINS] (mode 0)
    double* __restrict__ wsd,           // [2*BINS]     (mode 1)
    int nQuads, int nRows)
{
    __shared__ float hcnt[BINS][BLOCK];   // 10 KiB; lane->bank i%32, bin stride==0 mod banks
    __shared__ float hsum[BINS][BLOCK];   // 10 KiB
    const int tid = threadIdx.x;
#pragma unroll
    for (int b = 0; b < BINS; ++b) { hcnt[b][tid] = 0.f; hsum[b][tid] = 0.f; }
    // no sync needed: each thread touches only its own column until reduction

    float* cbase = &hcnt[0][tid];
    float* sbase = &hsum[0][tid];

    for (int i = blockIdx.x * BLOCK + tid; i < nQuads; i += GRID * BLOCK) {
        float4 pa = pred4[2 * i + 0];   // rows 4i, 4i+1
        float4 pb = pred4[2 * i + 1];   // rows 4i+2, 4i+3
        int4   tq = tgt4[i];
        proc_row(pa.x, pa.y, tq.x, cbase, sbase);
        proc_row(pa.z, pa.w, tq.y, cbase, sbase);
        proc_row(pb.x, pb.y, tq.z, cbase, sbase);
        proc_row(pb.z, pb.w, tq.w, cbase, sbase);
    }

    // defensive scalar tail (N divisible by 4 here)
    if (blockIdx.x == 0 && tid == 0) {
        const float* pf = (const float*)pred4;
        const int*   tf = (const int*)tgt4;
        for (int r = nQuads * 4; r < nRows; ++r)
            proc_row(pf[2 * r], pf[2 * r + 1], tf[r], cbase, sbase);
    }

    __syncthreads();

    // 256 -> 128 -> 64 in LDS, then wave-0 shuffle reduce
    if (tid < 128) {
#pragma unroll
        for (int b = 0; b < BINS; ++b) {
            hcnt[b][tid] += hcnt[b][tid + 128];
            hsum[b][tid] += hsum[b][tid + 128];
        }
    }
    __syncthreads();
    if (tid < 64) {
        float cx[BINS], cy[BINS];
#pragma unroll
        for (int b = 0; b < BINS; ++b) {
            cx[b] = hcnt[b][tid] + hcnt[b][tid + 64];
            cy[b] = hsum[b][tid] + hsum[b][tid + 64];
        }
#pragma unroll
        for (int off = 32; off > 0; off >>= 1) {
#pragma unroll
            for (int b = 0; b < BINS; ++b) {
                cx[b] += __shfl_down(cx[b], off, 64);
                cy[b] += __shfl_down(cy[b], off, 64);
            }
        }
        if (tid == 0) {
            if (WRITE_MODE == 0) {
#pragma unroll
                for (int b = 0; b < BINS; ++b)
                    partials[blockIdx.x * BINS + b] = make_float2(cx[b], cy[b]);
            } else {
#pragma unroll
                for (int b = 0; b < BINS; ++b) {
                    atomicAdd(&wsd[b],        (double)cx[b]);
                    atomicAdd(&wsd[BINS + b], (double)cy[b]);
                }
            }
        }
    }
}

__global__ __launch_bounds__(1024) void ghmc_final_grid(
    const float2* __restrict__ partials, float* __restrict__ out, int nb)
{
    const int tid  = threadIdx.x;
    const int wid  = tid >> 6;
    const int lane = tid & 63;
    double cx[BINS], cy[BINS];
#pragma unroll
    for (int b = 0; b < BINS; ++b) { cx[b] = 0.0; cy[b] = 0.0; }

    for (int p = tid; p < nb; p += 1024) {
#pragma unroll
        for (int b = 0; b < BINS; ++b) {
            float2 v = partials[p * BINS + b];
            cx[b] += (double)v.x;
            cy[b] += (double)v.y;
        }
    }
#pragma unroll
    for (int off = 32; off > 0; off >>= 1) {
#pragma unroll
        for (int b = 0; b < BINS; ++b) {
            cx[b] += __shfl_down(cx[b], off, 64);
            cy[b] += __shfl_down(cy[b], off, 64);
        }
    }
    __shared__ double2 wred[16][BINS];
    if (lane == 0) {
#pragma unroll
        for (int b = 0; b < BINS; ++b) wred[wid][b] = make_double2(cx[b], cy[b]);
    }
    __syncthreads();
    if (tid == 0) {
        int nz = 0;
        double acc = 0.0;
#pragma unroll
        for (int b = 0; b < BINS; ++b) {
            double c = 0.0, s = 0.0;
            for (int w = 0; w < 16; ++w) { c += wred[w][b].x; s += wred[w][b].y; }
            if (c > 0.0) { nz++; acc += s / c; }
        }
        out[0] = (float)((nz > 0) ? (acc / (double)nz) : 0.0);
    }
}

__global__ void ghmc_final_atomic(const double* __restrict__ ws, float* __restrict__ out) {
    if (threadIdx.x == 0) {
        int nz = 0;
        double acc = 0.0;
#pragma unroll
        for (int b = 0; b < BINS; ++b) {
            double c = ws[b];
            if (c > 0.0) { nz++; acc += ws[BINS + b] / c; }
        }
        out[0] = (float)((nz > 0) ? (acc / (double)nz) : 0.0);
    }
}

extern "C" void kernel_launch(void* const* d_in, const int* in_sizes, int n_in,
                              void* d_out, int out_size, void* d_ws, size_t ws_size,
                              hipStream_t stream) {
    const float* pred = (const float*)d_in[0];   // [N,2] float32
    const int* target = (const int*)d_in[1];     // [N] int32 (harness lowers int64)
    const int nRows = in_sizes[1];
    const int nQuads = nRows / 4;
    float* out = (float*)d_out;

    const size_t need = (size_t)GRID * BINS * sizeof(float2);  // 160 KiB
    if (ws_size >= need) {
        float2* partials = (float2*)d_ws;
        ghmc_main<0><<<GRID, BLOCK, 0, stream>>>(
            (const float4*)pred, (const int4*)target, partials, nullptr, nQuads, nRows);
        ghmc_final_grid<<<1, 1024, 0, stream>>>(partials, out, GRID);
    } else {
        double* wsd = (double*)d_ws;
        ghmc_init<<<1, 64, 0, stream>>>(wsd);
        ghmc_main<1><<<GRID, BLOCK, 0, stream>>>(
            (const float4*)pred, (const int4*)target, nullptr, wsd, nQuads, nRows);
        ghmc_final_atomic<<<1, 64, 0, stream>>>(wsd, out);
    }
}

// Round 6
// 66.094 us; speedup vs baseline: 2.9322x; 2.9322x over previous
//
#include <hip/hip_runtime.h>

#define BINS 10
#define BLOCK 256
#define GRID 2048

#define LOG2E 1.44269504088896340736f
#define LN2   0.69314718055994530942f

// ---------------------------------------------------------------------------
// For logit x with one-hot target bit tg, let y = tg ? -x : x. Then
//   g   = |sigmoid(x) - tg| = sigmoid(y)
//   bce = softplus(y) = ln(1 + e^y)
// bin(g) >= k  <=>  sigmoid(y) >= k/10  <=>  y >= logit(k/10) = ln(k/(10-k)).
// So we accumulate CUMULATIVE stats per threshold, entirely in registers:
//   S_k = sum of bce over logits with y >= L_k   (S_0 = all)
//   C_k = count of logits with y >= L_k          (C_0 = all)
// Counts go through __ballot + popcount -> wave-uniform scalars (SALU pipe,
// hidden under VALU). Per-bin values are differences, taken in the finalize.
// No LDS and no atomics in the hot loop.
// ---------------------------------------------------------------------------

__constant__ const float THR[9] = {
    -2.1972246f, -1.3862944f, -0.84729785f, -0.40546511f, 0.0f,
     0.40546511f, 0.84729785f, 1.3862944f,  2.1972246f };

__global__ void ghmc_init(double* ws) {
    int i = threadIdx.x;
    if (i < 2 * BINS) ws[i] = 0.0;
}

__device__ __forceinline__ void proc(float y, float* __restrict__ s,
                                     unsigned* __restrict__ c) {
    y = fminf(fmaxf(y, -80.0f), 80.0f);              // v_med3_f32 guard
    float u  = __builtin_amdgcn_exp2f(y * LOG2E);    // e^y
    float d  = 1.0f + u;
    float lg = __builtin_amdgcn_logf(d);             // log2(1+u)
    float sp = lg * LN2;                             // softplus(y) = bce
    s[0] += sp;
#pragma unroll
    for (int k = 0; k < 9; ++k) {
        bool cond = y >= THR[k];
        c[k] += (unsigned)__popcll(__ballot(cond));  // SALU: s_bcnt1 + s_add
        s[k + 1] += cond ? sp : 0.0f;                // v_cndmask + v_add
    }
}

__device__ __forceinline__ void proc_row(float x0, float x1, int t,
                                         float* __restrict__ s,
                                         unsigned* __restrict__ c) {
    // class0 flips iff t==0, class1 flips iff t==1 (t in {0,1})
    unsigned s0 = (unsigned)(t ^ 1) << 31;
    unsigned s1 = s0 ^ 0x80000000u;
    proc(__uint_as_float(__float_as_uint(x0) ^ s0), s, c);
    proc(__uint_as_float(__float_as_uint(x1) ^ s1), s, c);
}

template <int WRITE_MODE>  // 0 = per-block partials (deterministic), 1 = double atomics
__global__ __launch_bounds__(BLOCK, 8) void ghmc_main(
    const float4* __restrict__ pred4,   // one float4 = 2 rows' logits
    const int4*   __restrict__ tgt4,    // one int4   = 4 rows' targets (int32)
    float2* __restrict__ partials,      // [GRID][BINS] (mode 0): (C_k, S_k)
    double* __restrict__ wsd,           // [2*BINS]     (mode 1)
    int nQuads, int nRows)
{
    const int tid = threadIdx.x;
    float    s[BINS];      // cumulative bce sums, per-lane registers
    unsigned c0 = 0;       // total logits, wave-uniform
    unsigned c[9];         // cumulative counts per threshold, wave-uniform
#pragma unroll
    for (int b = 0; b < BINS; ++b) s[b] = 0.0f;
#pragma unroll
    for (int k = 0; k < 9; ++k) c[k] = 0u;

    for (int i = blockIdx.x * BLOCK + tid; i < nQuads; i += GRID * BLOCK) {
        float4 pa = pred4[2 * i + 0];   // rows 4i, 4i+1
        float4 pb = pred4[2 * i + 1];   // rows 4i+2, 4i+3
        int4   tq = tgt4[i];
        c0 += 8u * (unsigned)__popcll(__ballot(1));
        proc_row(pa.x, pa.y, tq.x, s, c);
        proc_row(pa.z, pa.w, tq.y, s, c);
        proc_row(pb.x, pb.y, tq.z, s, c);
        proc_row(pb.z, pb.w, tq.w, s, c);
    }

    // defensive scalar tail (N divisible by 4 here)
    if (blockIdx.x == 0 && tid == 0) {
        const float* pf = (const float*)pred4;
        const int*   tf = (const int*)tgt4;
        for (int r = nQuads * 4; r < nRows; ++r) {
            c0 += 2u * (unsigned)__popcll(__ballot(1));
            proc_row(pf[2 * r], pf[2 * r + 1], tf[r], s, c);
        }
    }

    // wave-level shuffle reduce of the per-lane sums (counts already uniform)
#pragma unroll
    for (int off = 32; off > 0; off >>= 1) {
#pragma unroll
        for (int b = 0; b < BINS; ++b) s[b] += __shfl_down(s[b], off, 64);
    }

    __shared__ float    sred[4][BINS];
    __shared__ unsigned cred[4][BINS];
    const int wid  = tid >> 6;
    const int lane = tid & 63;
    if (lane == 0) {
#pragma unroll
        for (int b = 0; b < BINS; ++b) sred[wid][b] = s[b];
        cred[wid][0] = c0;
#pragma unroll
        for (int k = 0; k < 9; ++k) cred[wid][k + 1] = c[k];
    }
    __syncthreads();

    if (tid < BINS) {
        float    S = 0.0f;
        unsigned C = 0u;
#pragma unroll
        for (int w = 0; w < 4; ++w) { S += sred[w][tid]; C += cred[w][tid]; }
        if (WRITE_MODE == 0) {
            partials[blockIdx.x * BINS + tid] = make_float2((float)C, S);
        } else {
            atomicAdd(&wsd[tid],        (double)C);
            atomicAdd(&wsd[BINS + tid], (double)S);
        }
    }
}

// partials hold CUMULATIVE (C_k, S_k); per-bin = difference of neighbors.
__global__ __launch_bounds__(1024) void ghmc_final_grid(
    const float2* __restrict__ partials, float* __restrict__ out, int nb)
{
    const int tid  = threadIdx.x;
    const int wid  = tid >> 6;
    const int lane = tid & 63;
    double cx[BINS], cy[BINS];
#pragma unroll
    for (int b = 0; b < BINS; ++b) { cx[b] = 0.0; cy[b] = 0.0; }

    for (int p = tid; p < nb; p += 1024) {
#pragma unroll
        for (int b = 0; b < BINS; ++b) {
            float2 v = partials[p * BINS + b];
            cx[b] += (double)v.x;
            cy[b] += (double)v.y;
        }
    }
#pragma unroll
    for (int off = 32; off > 0; off >>= 1) {
#pragma unroll
        for (int b = 0; b < BINS; ++b) {
            cx[b] += __shfl_down(cx[b], off, 64);
            cy[b] += __shfl_down(cy[b], off, 64);
        }
    }
    __shared__ double2 wred[16][BINS];
    if (lane == 0) {
#pragma unroll
        for (int b = 0; b < BINS; ++b) wred[wid][b] = make_double2(cx[b], cy[b]);
    }
    __syncthreads();
    if (tid == 0) {
        double C[BINS + 1], S[BINS + 1];
#pragma unroll
        for (int b = 0; b < BINS; ++b) {
            double c = 0.0, ssum = 0.0;
            for (int w = 0; w < 16; ++w) { c += wred[w][b].x; ssum += wred[w][b].y; }
            C[b] = c; S[b] = ssum;
        }
        C[BINS] = 0.0; S[BINS] = 0.0;
        int nz = 0;
        double acc = 0.0;
#pragma unroll
        for (int b = 0; b < BINS; ++b) {
            double cnt = C[b] - C[b + 1];
            double sm  = S[b] - S[b + 1];
            if (cnt > 0.0) { nz++; acc += sm / cnt; }
        }
        out[0] = (float)((nz > 0) ? (acc / (double)nz) : 0.0);
    }
}

__global__ void ghmc_final_atomic(const double* __restrict__ ws, float* __restrict__ out) {
    if (threadIdx.x == 0) {
        int nz = 0;
        double acc = 0.0;
#pragma unroll
        for (int b = 0; b < BINS; ++b) {
            double cnt = ws[b]        - ((b + 1 < BINS) ? ws[b + 1]        : 0.0);
            double sm  = ws[BINS + b] - ((b + 1 < BINS) ? ws[BINS + b + 1] : 0.0);
            if (cnt > 0.0) { nz++; acc += sm / cnt; }
        }
        out[0] = (float)((nz > 0) ? (acc / (double)nz) : 0.0);
    }
}

extern "C" void kernel_launch(void* const* d_in, const int* in_sizes, int n_in,
                              void* d_out, int out_size, void* d_ws, size_t ws_size,
                              hipStream_t stream) {
    const float* pred = (const float*)d_in[0];   // [N,2] float32
    const int* target = (const int*)d_in[1];     // [N] int32 (harness lowers int64)
    const int nRows = in_sizes[1];
    const int nQuads = nRows / 4;
    float* out = (float*)d_out;

    const size_t need = (size_t)GRID * BINS * sizeof(float2);  // 160 KiB
    if (ws_size >= need) {
        float2* partials = (float2*)d_ws;
        ghmc_main<0><<<GRID, BLOCK, 0, stream>>>(
            (const float4*)pred, (const int4*)target, partials, nullptr, nQuads, nRows);
        ghmc_final_grid<<<1, 1024, 0, stream>>>(partials, out, GRID);
    } else {
        double* wsd = (double*)d_ws;
        ghmc_init<<<1, 64, 0, stream>>>(wsd);
        ghmc_main<1><<<GRID, BLOCK, 0, stream>>>(
            (const float4*)pred, (const int4*)target, nullptr, wsd, nQuads, nRows);
        ghmc_final_atomic<<<1, 64, 0, stream>>>(wsd, out);
    }
}

// Round 7
// 36.183 us; speedup vs baseline: 5.3561x; 1.8266x over previous
//
#include <hip/hip_runtime.h>

#define BINS 10
#define BLOCK 256
#define GRID 2048
#define RED1_BLOCKS 32
#define CHUNK (GRID / RED1_BLOCKS)   // 64 = one wave's worth

#define LOG2E 1.44269504088896340736f
#define LN2   0.69314718055994530942f

// ---------------------------------------------------------------------------
// For logit x with one-hot target bit tg, let y = tg ? -x : x. Then
//   g   = |sigmoid(x) - tg| = sigmoid(y)
//   bce = softplus(y) = ln(1 + e^y)
// bin(g) >= k  <=>  y >= logit(k/10).  Accumulate CUMULATIVE stats per
// threshold in registers; counts via ballot+popcount (SALU). Per-bin values
// are neighbor differences, taken in the last reduce stage.
//
// ws layout: float2 partials[BINS][GRID] (SoA, 160 KiB) at offset 0,
//            double2 partials2[RED1_BLOCKS][BINS] (5 KiB) right after.
// ---------------------------------------------------------------------------

__constant__ const float THR[9] = {
    -2.1972246f, -1.3862944f, -0.84729785f, -0.40546511f, 0.0f,
     0.40546511f, 0.84729785f, 1.3862944f,  2.1972246f };

__global__ void ghmc_init(double* ws) {
    int i = threadIdx.x;
    if (i < 2 * BINS) ws[i] = 0.0;
}

__device__ __forceinline__ void proc(float y, float* __restrict__ s,
                                     unsigned* __restrict__ c) {
    y = fminf(fmaxf(y, -80.0f), 80.0f);              // v_med3_f32 guard
    float u  = __builtin_amdgcn_exp2f(y * LOG2E);    // e^y
    float d  = 1.0f + u;
    float lg = __builtin_amdgcn_logf(d);             // log2(1+u)
    float sp = lg * LN2;                             // softplus(y) = bce
    s[0] += sp;
#pragma unroll
    for (int k = 0; k < 9; ++k) {
        bool cond = y >= THR[k];
        c[k] += (unsigned)__popcll(__ballot(cond));  // SALU: s_bcnt1 + s_add
        s[k + 1] += cond ? sp : 0.0f;                // v_cndmask + v_add
    }
}

__device__ __forceinline__ void proc_row(float x0, float x1, int t,
                                         float* __restrict__ s,
                                         unsigned* __restrict__ c) {
    // class0 flips iff t==0, class1 flips iff t==1 (t in {0,1})
    unsigned s0 = (unsigned)(t ^ 1) << 31;
    unsigned s1 = s0 ^ 0x80000000u;
    proc(__uint_as_float(__float_as_uint(x0) ^ s0), s, c);
    proc(__uint_as_float(__float_as_uint(x1) ^ s1), s, c);
}

template <int WRITE_MODE>  // 0 = SoA per-block partials (deterministic), 1 = double atomics
__global__ __launch_bounds__(BLOCK, 8) void ghmc_main(
    const float4* __restrict__ pred4,   // one float4 = 2 rows' logits
    const int4*   __restrict__ tgt4,    // one int4   = 4 rows' targets (int32)
    float2* __restrict__ partials,      // [BINS][GRID] SoA (mode 0): (C_k, S_k)
    double* __restrict__ wsd,           // [2*BINS]          (mode 1)
    int nQuads, int nRows)
{
    const int tid = threadIdx.x;
    float    s[BINS];      // cumulative bce sums, per-lane registers
    unsigned c0 = 0;       // total logits, wave-uniform
    unsigned c[9];         // cumulative counts per threshold, wave-uniform
#pragma unroll
    for (int b = 0; b < BINS; ++b) s[b] = 0.0f;
#pragma unroll
    for (int k = 0; k < 9; ++k) c[k] = 0u;

    for (int i = blockIdx.x * BLOCK + tid; i < nQuads; i += GRID * BLOCK) {
        float4 pa = pred4[2 * i + 0];   // rows 4i, 4i+1
        float4 pb = pred4[2 * i + 1];   // rows 4i+2, 4i+3
        int4   tq = tgt4[i];
        c0 += 8u * (unsigned)__popcll(__ballot(1));
        proc_row(pa.x, pa.y, tq.x, s, c);
        proc_row(pa.z, pa.w, tq.y, s, c);
        proc_row(pb.x, pb.y, tq.z, s, c);
        proc_row(pb.z, pb.w, tq.w, s, c);
    }

    // defensive scalar tail (N divisible by 4 here)
    if (blockIdx.x == 0 && tid == 0) {
        const float* pf = (const float*)pred4;
        const int*   tf = (const int*)tgt4;
        for (int r = nQuads * 4; r < nRows; ++r) {
            c0 += 2u * (unsigned)__popcll(__ballot(1));
            proc_row(pf[2 * r], pf[2 * r + 1], tf[r], s, c);
        }
    }

    // wave-level shuffle reduce of the per-lane sums (counts already uniform)
#pragma unroll
    for (int off = 32; off > 0; off >>= 1) {
#pragma unroll
        for (int b = 0; b < BINS; ++b) s[b] += __shfl_down(s[b], off, 64);
    }

    __shared__ float    sred[4][BINS];
    __shared__ unsigned cred[4][BINS];
    const int wid  = tid >> 6;
    const int lane = tid & 63;
    if (lane == 0) {
#pragma unroll
        for (int b = 0; b < BINS; ++b) sred[wid][b] = s[b];
        cred[wid][0] = c0;
#pragma unroll
        for (int k = 0; k < 9; ++k) cred[wid][k + 1] = c[k];
    }
    __syncthreads();

    if (tid < BINS) {
        float    S = 0.0f;
        unsigned C = 0u;
#pragma unroll
        for (int w = 0; w < 4; ++w) { S += sred[w][tid]; C += cred[w][tid]; }
        if (WRITE_MODE == 0) {
            partials[tid * GRID + blockIdx.x] = make_float2((float)C, S);  // SoA
        } else {
            atomicAdd(&wsd[tid],        (double)C);
            atomicAdd(&wsd[BINS + tid], (double)S);
        }
    }
}

// Stage 1: 32 blocks x 1 wave; block j reduces partials[k][j*64 .. j*64+63]
// (one coalesced 512-B load per bin) into partials2[j][k]. Spread across 32
// CUs -> 32x the miss parallelism of the old single-block gather.
__global__ __launch_bounds__(64) void ghmc_red1(
    const float2* __restrict__ partials,    // [BINS][GRID]
    double2* __restrict__ partials2)        // [RED1_BLOCKS][BINS]
{
    const int lane = threadIdx.x;
    const int j = blockIdx.x;
#pragma unroll
    for (int k = 0; k < BINS; ++k) {
        float2 v = partials[k * GRID + j * CHUNK + lane];
        double cx = (double)v.x;
        double cy = (double)v.y;
#pragma unroll
        for (int off = 32; off > 0; off >>= 1) {
            cx += __shfl_down(cx, off, 64);
            cy += __shfl_down(cy, off, 64);
        }
        if (lane == 0) partials2[j * BINS + k] = make_double2(cx, cy);
    }
}

// Stage 2: one wave; lane j < 32 holds block j's row, shuffle-reduce, then
// cumulative-difference finalize on lane 0.
__global__ __launch_bounds__(64) void ghmc_red2(
    const double2* __restrict__ partials2, float* __restrict__ out)
{
    const int lane = threadIdx.x;
    double cx[BINS], cy[BINS];
#pragma unroll
    for (int b = 0; b < BINS; ++b) { cx[b] = 0.0; cy[b] = 0.0; }
    if (lane < RED1_BLOCKS) {
#pragma unroll
        for (int b = 0; b < BINS; ++b) {
            double2 v = partials2[lane * BINS + b];
            cx[b] = v.x; cy[b] = v.y;
        }
    }
#pragma unroll
    for (int off = 32; off > 0; off >>= 1) {
#pragma unroll
        for (int b = 0; b < BINS; ++b) {
            cx[b] += __shfl_down(cx[b], off, 64);
            cy[b] += __shfl_down(cy[b], off, 64);
        }
    }
    if (lane == 0) {
        int nz = 0;
        double acc = 0.0;
#pragma unroll
        for (int b = 0; b < BINS; ++b) {
            double cnt = cx[b] - ((b + 1 < BINS) ? cx[b + 1] : 0.0);
            double sm  = cy[b] - ((b + 1 < BINS) ? cy[b + 1] : 0.0);
            if (cnt > 0.0) { nz++; acc += sm / cnt; }
        }
        out[0] = (float)((nz > 0) ? (acc / (double)nz) : 0.0);
    }
}

__global__ void ghmc_final_atomic(const double* __restrict__ ws, float* __restrict__ out) {
    if (threadIdx.x == 0) {
        int nz = 0;
        double acc = 0.0;
#pragma unroll
        for (int b = 0; b < BINS; ++b) {
            double cnt = ws[b]        - ((b + 1 < BINS) ? ws[b + 1]        : 0.0);
            double sm  = ws[BINS + b] - ((b + 1 < BINS) ? ws[BINS + b + 1] : 0.0);
            if (cnt > 0.0) { nz++; acc += sm / cnt; }
        }
        out[0] = (float)((nz > 0) ? (acc / (double)nz) : 0.0);
    }
}

extern "C" void kernel_launch(void* const* d_in, const int* in_sizes, int n_in,
                              void* d_out, int out_size, void* d_ws, size_t ws_size,
                              hipStream_t stream) {
    const float* pred = (const float*)d_in[0];   // [N,2] float32
    const int* target = (const int*)d_in[1];     // [N] int32 (harness lowers int64)
    const int nRows = in_sizes[1];
    const int nQuads = nRows / 4;
    float* out = (float*)d_out;

    const size_t partials_bytes = (size_t)BINS * GRID * sizeof(float2);   // 160 KiB
    const size_t need = partials_bytes + (size_t)RED1_BLOCKS * BINS * sizeof(double2);
    if (ws_size >= need) {
        float2*  partials  = (float2*)d_ws;
        double2* partials2 = (double2*)((char*)d_ws + partials_bytes);
        ghmc_main<0><<<GRID, BLOCK, 0, stream>>>(
            (const float4*)pred, (const int4*)target, partials, nullptr, nQuads, nRows);
        ghmc_red1<<<RED1_BLOCKS, 64, 0, stream>>>(partials, partials2);
        ghmc_red2<<<1, 64, 0, stream>>>(partials2, out);
    } else {
        double* wsd = (double*)d_ws;
        ghmc_init<<<1, 64, 0, stream>>>(wsd);
        ghmc_main<1><<<GRID, BLOCK, 0, stream>>>(
            (const float4*)pred, (const int4*)target, nullptr, wsd, nQuads, nRows);
        ghmc_final_atomic<<<1, 64, 0, stream>>>(wsd, out);
    }
}